// Round 1
// baseline (1516.128 us; speedup 1.0000x reference)
//
#include <hip/hip_runtime.h>
#include <math.h>

#define HH 240
#define WW 240
#define PP (HH * WW)
#define LOG_MAX_C 4.605170185988091f  // log(100)

// ---------------------------------------------------------------------------
// Direct 3x3 conv, stride 1, pad 1 (SAME), fp32, NCHW, OIHW weights.
// Block: 16x16 spatial tile; each thread computes OCPB output channels at one
// pixel so each input load (L1-hit) feeds OCPB FMAs. Weight indices are
// block-uniform -> scalar loads (broadcast, off the VALU critical path).
// 240/16 = 15 exactly: no output bounds checks needed.
// ---------------------------------------------------------------------------
template <int OCPB>
__global__ __launch_bounds__(256) void conv3x3_kernel(
    const float* __restrict__ in, const float* __restrict__ wgt,
    const float* __restrict__ bias, float* __restrict__ out, int IC)
{
    const int tx = threadIdx.x, ty = threadIdx.y;
    const int ox = blockIdx.x * 16 + tx;
    const int oy = blockIdx.y * 16 + ty;
    const int oc0 = blockIdx.z * OCPB;

    float acc[OCPB];
#pragma unroll
    for (int o = 0; o < OCPB; ++o) acc[o] = bias[oc0 + o];

    const int iy0 = oy - 1;
    const int ix0 = ox - 1;

    for (int ic = 0; ic < IC; ++ic) {
        const float* __restrict__ ip = in + ic * PP;
        const float* __restrict__ wp = wgt + (oc0 * IC + ic) * 9;
#pragma unroll
        for (int ky = 0; ky < 3; ++ky) {
            const int iy = iy0 + ky;
            const bool vy = ((unsigned)iy < (unsigned)HH);
#pragma unroll
            for (int kx = 0; kx < 3; ++kx) {
                const int ix = ix0 + kx;
                const bool v = vy && ((unsigned)ix < (unsigned)WW);
                const float val = v ? ip[iy * WW + ix] : 0.0f;
#pragma unroll
                for (int o = 0; o < OCPB; ++o)
                    acc[o] += val * wp[o * IC * 9 + ky * 3 + kx];
            }
        }
    }
#pragma unroll
    for (int o = 0; o < OCPB; ++o)
        out[(oc0 + o) * PP + oy * WW + ox] = acc[o];
}

// ---------------------------------------------------------------------------
// Window cosine attention: WS=5 (25 tokens), NH=8, hd=4.
// One block per window; threads 0..199 map to (head h = t/25, token i = t%25).
// gshift: input gather roll (+3 for shifted branch), sshift: output scatter
// roll (+2 for shifted branch) -- matches torch's asymmetric roll(-3)/roll(+2).
// fq: 32-ch q source; kv: 64-ch (first 32 = K, last 32 = V); out: 32-ch.
// ---------------------------------------------------------------------------
__global__ __launch_bounds__(256) void win_attn_kernel(
    const float* __restrict__ fq, const float* __restrict__ kv,
    const float* __restrict__ lsc, float* __restrict__ out,
    int gshift, int sshift)
{
    __shared__ float ks[8][25][4];
    __shared__ float vs[8][25][4];
    const int t = threadIdx.x;
    const int wy = blockIdx.y, wx = blockIdx.x;
    const int h = t / 25, i = t % 25;
    float qn[4] = {0, 0, 0, 0};
    int oy = 0, ox = 0;

    if (t < 200) {
        const int y = (wy * 5 + i / 5 + gshift) % HH;
        const int x = (wx * 5 + i % 5 + gshift) % WW;
        const int base = y * WW + x;
        float q[4], k[4];
        float qsq = 0.f, ksq = 0.f;
#pragma unroll
        for (int d = 0; d < 4; ++d) {
            q[d] = fq[(h * 4 + d) * PP + base];
            k[d] = kv[(h * 4 + d) * PP + base];
            vs[h][i][d] = kv[((8 + h) * 4 + d) * PP + base];
            qsq += q[d] * q[d];
            ksq += k[d] * k[d];
        }
        const float qinv = 1.0f / fmaxf(sqrtf(qsq), 1e-12f);
        const float kinv = 1.0f / fmaxf(sqrtf(ksq), 1e-12f);
#pragma unroll
        for (int d = 0; d < 4; ++d) {
            qn[d] = q[d] * qinv;
            ks[h][i][d] = k[d] * kinv;
        }
        oy = (wy * 5 + i / 5 + sshift) % HH;
        ox = (wx * 5 + i % 5 + sshift) % WW;
    }
    __syncthreads();
    if (t < 200) {
        const float scale = __expf(fminf(lsc[h], LOG_MAX_C));
        float s[25], m = -1e30f;
#pragma unroll
        for (int j = 0; j < 25; ++j) {
            const float d0 = qn[0] * ks[h][j][0] + qn[1] * ks[h][j][1] +
                             qn[2] * ks[h][j][2] + qn[3] * ks[h][j][3];
            s[j] = d0 * scale;
            m = fmaxf(m, s[j]);
        }
        float l = 0.f, acc[4] = {0, 0, 0, 0};
#pragma unroll
        for (int j = 0; j < 25; ++j) {
            const float p = __expf(s[j] - m);
            l += p;
#pragma unroll
            for (int d = 0; d < 4; ++d) acc[d] += p * vs[h][j][d];
        }
        const float linv = 1.0f / l;
#pragma unroll
        for (int d = 0; d < 4; ++d)
            out[(h * 4 + d) * PP + oy * WW + ox] = acc[d] * linv;
    }
}

// ---------------------------------------------------------------------------
// Axial row attention (attend over w within each row y). One block per
// (row y, head h). Threads 0..239 = query position i along the row.
// Online softmax over j=0..239, K/V staged (normalized) in LDS.
// Writes row-attn output v1 (32 ch) to workspace.
// ---------------------------------------------------------------------------
__global__ __launch_bounds__(256) void axial_row_kernel(
    const float* __restrict__ fq, const float* __restrict__ kv,
    const float* __restrict__ lsc, float* __restrict__ v1)
{
    __shared__ float ks[240][4];
    __shared__ float vs[240][4];
    const int t = threadIdx.x;
    const int y = blockIdx.x, h = blockIdx.y;

    if (t < 240) {
        float k[4];
        float ksq = 0.f;
#pragma unroll
        for (int d = 0; d < 4; ++d) {
            k[d] = kv[(h * 4 + d) * PP + y * WW + t];
            vs[t][d] = kv[((8 + h) * 4 + d) * PP + y * WW + t];
            ksq += k[d] * k[d];
        }
        const float kinv = 1.0f / fmaxf(sqrtf(ksq), 1e-12f);
#pragma unroll
        for (int d = 0; d < 4; ++d) ks[t][d] = k[d] * kinv;
    }
    __syncthreads();
    if (t < 240) {
        float q[4];
        float qsq = 0.f;
#pragma unroll
        for (int d = 0; d < 4; ++d) {
            q[d] = fq[(h * 4 + d) * PP + y * WW + t];
            qsq += q[d] * q[d];
        }
        const float qinv = 1.0f / fmaxf(sqrtf(qsq), 1e-12f);
#pragma unroll
        for (int d = 0; d < 4; ++d) q[d] *= qinv;
        const float scale = __expf(fminf(lsc[h], LOG_MAX_C));
        float m = -1e30f, l = 0.f, acc[4] = {0, 0, 0, 0};
        for (int j = 0; j < 240; ++j) {
            const float s = (q[0] * ks[j][0] + q[1] * ks[j][1] +
                             q[2] * ks[j][2] + q[3] * ks[j][3]) * scale;
            const float mn = fmaxf(m, s);
            const float c = __expf(m - mn);
            const float p = __expf(s - mn);
            l = l * c + p;
#pragma unroll
            for (int d = 0; d < 4; ++d) acc[d] = acc[d] * c + p * vs[j][d];
            m = mn;
        }
        const float linv = 1.0f / l;
#pragma unroll
        for (int d = 0; d < 4; ++d)
            v1[(h * 4 + d) * PP + y * WW + t] = acc[d] * linv;
    }
}

// ---------------------------------------------------------------------------
// Axial column attention (attend over h within each column x), using the SAME
// normalized q/k as the row pass (per reference) and the row output v1 as V.
// One block per (column x, head h); threads 0..239 = query row i.
// ---------------------------------------------------------------------------
__global__ __launch_bounds__(256) void axial_col_kernel(
    const float* __restrict__ fq, const float* __restrict__ kv,
    const float* __restrict__ v1, const float* __restrict__ lsc,
    float* __restrict__ out)
{
    __shared__ float ks[240][4];
    __shared__ float vs[240][4];
    const int t = threadIdx.x;
    const int x = blockIdx.x, h = blockIdx.y;

    if (t < 240) {
        float k[4];
        float ksq = 0.f;
#pragma unroll
        for (int d = 0; d < 4; ++d) {
            k[d] = kv[(h * 4 + d) * PP + t * WW + x];
            vs[t][d] = v1[(h * 4 + d) * PP + t * WW + x];
            ksq += k[d] * k[d];
        }
        const float kinv = 1.0f / fmaxf(sqrtf(ksq), 1e-12f);
#pragma unroll
        for (int d = 0; d < 4; ++d) ks[t][d] = k[d] * kinv;
    }
    __syncthreads();
    if (t < 240) {
        float q[4];
        float qsq = 0.f;
#pragma unroll
        for (int d = 0; d < 4; ++d) {
            q[d] = fq[(h * 4 + d) * PP + t * WW + x];
            qsq += q[d] * q[d];
        }
        const float qinv = 1.0f / fmaxf(sqrtf(qsq), 1e-12f);
#pragma unroll
        for (int d = 0; d < 4; ++d) q[d] *= qinv;
        const float scale = __expf(fminf(lsc[h], LOG_MAX_C));
        float m = -1e30f, l = 0.f, acc[4] = {0, 0, 0, 0};
        for (int j = 0; j < 240; ++j) {
            const float s = (q[0] * ks[j][0] + q[1] * ks[j][1] +
                             q[2] * ks[j][2] + q[3] * ks[j][3]) * scale;
            const float mn = fmaxf(m, s);
            const float c = __expf(m - mn);
            const float p = __expf(s - mn);
            l = l * c + p;
#pragma unroll
            for (int d = 0; d < 4; ++d) acc[d] = acc[d] * c + p * vs[j][d];
            m = mn;
        }
        const float linv = 1.0f / l;
#pragma unroll
        for (int d = 0; d < 4; ++d)
            out[(h * 4 + d) * PP + t * WW + x] = acc[d] * linv;
    }
}

// ---------------------------------------------------------------------------
// kernel_launch: x -> conv_in (192ch xp), conv_f (96ch fp);
// branch0 = win-attn(fp[0:32], xp[0:64]); branch1 = shifted win-attn;
// branch2 = axial row+col; concat -> conv_out -> d_out.
// Workspace: xp(192P) | fp(96P) | ycat(96P) | v1(32P)  = ~95.8 MB floats.
// ---------------------------------------------------------------------------
extern "C" void kernel_launch(void* const* d_in, const int* in_sizes, int n_in,
                              void* d_out, int out_size, void* d_ws, size_t ws_size,
                              hipStream_t stream)
{
    const float* x     = (const float*)d_in[0];
    const float* w_in  = (const float*)d_in[1];
    const float* b_in  = (const float*)d_in[2];
    const float* w_f   = (const float*)d_in[3];
    const float* b_f   = (const float*)d_in[4];
    const float* w_out = (const float*)d_in[5];
    const float* b_out = (const float*)d_in[6];
    const float* lsc   = (const float*)d_in[7];
    const float* lrlsc = (const float*)d_in[8];
    float* out = (float*)d_out;

    float* ws   = (float*)d_ws;
    float* xp   = ws;                     // 192 * PP
    float* fp   = xp + 192 * PP;          //  96 * PP
    float* ycat = fp + 96 * PP;           //  96 * PP
    float* v1   = ycat + 96 * PP;         //  32 * PP

    const dim3 cblk(16, 16);
    // conv_in: 96 -> 192
    conv3x3_kernel<8><<<dim3(15, 15, 24), cblk, 0, stream>>>(x, w_in, b_in, xp, 96);
    // conv_f: 96 -> 96
    conv3x3_kernel<8><<<dim3(15, 15, 12), cblk, 0, stream>>>(x, w_f, b_f, fp, 96);

    // branch 0: plain windows
    win_attn_kernel<<<dim3(48, 48), 256, 0, stream>>>(
        fp, xp, lsc, ycat, 0, 0);
    // branch 1: shifted windows (gather +3, scatter +2 — matches roll(-3)/roll(+2))
    win_attn_kernel<<<dim3(48, 48), 256, 0, stream>>>(
        fp + 32 * PP, xp + 64 * PP, lsc, ycat + 32 * PP, 3, 2);

    // branch 2: axial row then column
    axial_row_kernel<<<dim3(240, 8), 256, 0, stream>>>(
        fp + 64 * PP, xp + 128 * PP, lrlsc, v1);
    axial_col_kernel<<<dim3(240, 8), 256, 0, stream>>>(
        fp + 64 * PP, xp + 128 * PP, v1, lrlsc, ycat + 64 * PP);

    // conv_out: 96 -> 96
    conv3x3_kernel<8><<<dim3(15, 15, 12), cblk, 0, stream>>>(ycat, w_out, b_out, out, 96);
}

// Round 2
// 493.853 us; speedup vs baseline: 3.0700x; 3.0700x over previous
//
#include <hip/hip_runtime.h>
#include <math.h>

#define HH 240
#define WW 240
#define PP (HH * WW)
#define PW 242              // padded width/height for NHWC bf16 conv input
#define LOG_MAX_C 4.605170185988091f  // log(100)

typedef __bf16 bf16x8 __attribute__((ext_vector_type(8)));
typedef float  f32x4  __attribute__((ext_vector_type(4)));

// ---------------------------------------------------------------------------
// x (fp32 NCHW, 96ch, 240x240) -> xh (bf16 NHWC, zero-padded 242x242x96).
// One thread per padded pixel; reads coalesced across lanes per-ic, writes
// 12 x 16B contiguous per thread.
// ---------------------------------------------------------------------------
__global__ __launch_bounds__(256) void to_nhwc_pad(
    const float* __restrict__ in, __bf16* __restrict__ outh)
{
    const int p = blockIdx.x * 256 + threadIdx.x;
    if (p >= PW * PW) return;
    const int py = p / PW, px = p % PW;
    __bf16* op = outh + p * 96;
    union { __bf16 h[8]; uint4 u; } pk;
    if (py == 0 || py == PW - 1 || px == 0 || px == PW - 1) {
        pk.u = make_uint4(0, 0, 0, 0);
#pragma unroll
        for (int b = 0; b < 12; ++b) ((uint4*)op)[b] = pk.u;
    } else {
        const float* ip = in + (py - 1) * WW + (px - 1);
#pragma unroll
        for (int b = 0; b < 12; ++b) {
#pragma unroll
            for (int j = 0; j < 8; ++j)
                pk.h[j] = (__bf16)ip[(b * 8 + j) * PP];
            ((uint4*)op)[b] = pk.u;
        }
    }
}

// ---------------------------------------------------------------------------
// OIHW fp32 weights -> wt[tap][oc][ic] bf16 (tap = ky*3+kx). One thread per
// (oc,ic); 9 contiguous reads, 9 strided bf16 writes (coalesced in ic).
// ---------------------------------------------------------------------------
__global__ __launch_bounds__(256) void wt_transform(
    const float* __restrict__ w, __bf16* __restrict__ wt, int OC)
{
    const int t = blockIdx.x * 256 + threadIdx.x;
    if (t >= OC * 96) return;
    const int oc = t / 96, ic = t % 96;
    const float* wp = w + t * 9;
#pragma unroll
    for (int tap = 0; tap < 9; ++tap)
        wt[(tap * OC + oc) * 96 + ic] = (__bf16)wp[tap];
}

__global__ __launch_bounds__(256) void zero_u4(uint4* __restrict__ p, int n16)
{
    const int i = blockIdx.x * 256 + threadIdx.x;
    if (i < n16) p[i] = make_uint4(0, 0, 0, 0);
}

// ---------------------------------------------------------------------------
// Implicit-GEMM 3x3 conv on MFMA. A = weights wt[tap][oc][ic] (bf16),
// B = padded NHWC input xh (bf16), D = fp32 NCHW out (+bias).
// Block: 32 oc x (16x x 8y) px; 4 waves; wave w covers rows y0+2w, y0+2w+1.
// K-loop: 9 taps x 3 ic-chunks of 32 -> mfma_f32_16x16x32_bf16, 4 tiles/wave.
// Frag loads are single contiguous 16B/lane (ic-contiguous NHWC / [oc][ic]).
// C/D layout: col(px) = lane&15, row(oc) = quad*4 + reg  [m89-verified].
// ---------------------------------------------------------------------------
template <int OC>
__global__ __launch_bounds__(256) void conv3x3_mfma(
    const __bf16* __restrict__ xh, const __bf16* __restrict__ wt,
    const float* __restrict__ bias, float* __restrict__ out)
{
    const int wave = threadIdx.x >> 6;
    const int lane = threadIdx.x & 63;
    const int ln   = lane & 15;   // A: oc-in-tile; B: px-in-tile
    const int quad = lane >> 4;   // k-octet
    const int x0  = blockIdx.x * 16;
    const int y0  = blockIdx.y * 8;
    const int oc0 = blockIdx.z * 32;
    const int r0  = y0 + wave * 2;

    f32x4 acc[2][2] = {};  // [mi][ni]

    const __bf16* aptr = wt + (size_t)(oc0 + ln) * 96 + quad * 8;
    const __bf16* bptr = xh + (size_t)(x0 + ln) * 96 + quad * 8;

#pragma unroll 1
    for (int dy = 0; dy < 3; ++dy) {
        const __bf16* brow0 = bptr + (size_t)(r0 + dy) * PW * 96;
        const __bf16* arow  = aptr + (size_t)(dy * 3) * OC * 96;
#pragma unroll
        for (int dx = 0; dx < 3; ++dx) {
            const __bf16* ap  = arow + (size_t)dx * OC * 96;
            const __bf16* bp0 = brow0 + dx * 96;
            const __bf16* bp1 = bp0 + PW * 96;
#pragma unroll
            for (int icb = 0; icb < 3; ++icb) {
                const int ic0 = icb * 32;
                bf16x8 a0 = *(const bf16x8*)(ap + ic0);
                bf16x8 a1 = *(const bf16x8*)(ap + 16 * 96 + ic0);
                bf16x8 b0 = *(const bf16x8*)(bp0 + ic0);
                bf16x8 b1 = *(const bf16x8*)(bp1 + ic0);
                acc[0][0] = __builtin_amdgcn_mfma_f32_16x16x32_bf16(a0, b0, acc[0][0], 0, 0, 0);
                acc[1][0] = __builtin_amdgcn_mfma_f32_16x16x32_bf16(a1, b0, acc[1][0], 0, 0, 0);
                acc[0][1] = __builtin_amdgcn_mfma_f32_16x16x32_bf16(a0, b1, acc[0][1], 0, 0, 0);
                acc[1][1] = __builtin_amdgcn_mfma_f32_16x16x32_bf16(a1, b1, acc[1][1], 0, 0, 0);
            }
        }
    }

#pragma unroll
    for (int mi = 0; mi < 2; ++mi) {
#pragma unroll
        for (int r = 0; r < 4; ++r) {
            const int oc = oc0 + mi * 16 + quad * 4 + r;
            const float bv = bias[oc];
#pragma unroll
            for (int ni = 0; ni < 2; ++ni) {
                out[(size_t)oc * PP + (r0 + ni) * WW + x0 + ln] = acc[mi][ni][r] + bv;
            }
        }
    }
}

// ---------------------------------------------------------------------------
// Window cosine attention: WS=5 (25 tokens), NH=8, hd=4. One block / window.
// Writes result as bf16 directly into padded-NHWC ych at channel choff+h*4.
// ---------------------------------------------------------------------------
__global__ __launch_bounds__(256) void win_attn_kernel(
    const float* __restrict__ fq, const float* __restrict__ kv,
    const float* __restrict__ lsc, __bf16* __restrict__ ych,
    int gshift, int sshift, int choff)
{
    __shared__ float ks[8][25][4];
    __shared__ float vs[8][25][4];
    const int t = threadIdx.x;
    const int wy = blockIdx.y, wx = blockIdx.x;
    const int h = t / 25, i = t % 25;
    float qn[4] = {0, 0, 0, 0};
    int oy = 0, ox = 0;

    if (t < 200) {
        const int y = (wy * 5 + i / 5 + gshift) % HH;
        const int x = (wx * 5 + i % 5 + gshift) % WW;
        const int base = y * WW + x;
        float q[4], k[4];
        float qsq = 0.f, ksq = 0.f;
#pragma unroll
        for (int d = 0; d < 4; ++d) {
            q[d] = fq[(h * 4 + d) * PP + base];
            k[d] = kv[(h * 4 + d) * PP + base];
            vs[h][i][d] = kv[((8 + h) * 4 + d) * PP + base];
            qsq += q[d] * q[d];
            ksq += k[d] * k[d];
        }
        const float qinv = 1.0f / fmaxf(sqrtf(qsq), 1e-12f);
        const float kinv = 1.0f / fmaxf(sqrtf(ksq), 1e-12f);
#pragma unroll
        for (int d = 0; d < 4; ++d) {
            qn[d] = q[d] * qinv;
            ks[h][i][d] = k[d] * kinv;
        }
        oy = (wy * 5 + i / 5 + sshift) % HH;
        ox = (wx * 5 + i % 5 + sshift) % WW;
    }
    __syncthreads();
    if (t < 200) {
        const float scale = __expf(fminf(lsc[h], LOG_MAX_C));
        float s[25], m = -1e30f;
#pragma unroll
        for (int j = 0; j < 25; ++j) {
            const float d0 = qn[0] * ks[h][j][0] + qn[1] * ks[h][j][1] +
                             qn[2] * ks[h][j][2] + qn[3] * ks[h][j][3];
            s[j] = d0 * scale;
            m = fmaxf(m, s[j]);
        }
        float l = 0.f, acc[4] = {0, 0, 0, 0};
#pragma unroll
        for (int j = 0; j < 25; ++j) {
            const float p = __expf(s[j] - m);
            l += p;
#pragma unroll
            for (int d = 0; d < 4; ++d) acc[d] += p * vs[h][j][d];
        }
        const float linv = 1.0f / l;
        union { __bf16 h4[4]; uint2 u; } o;
#pragma unroll
        for (int d = 0; d < 4; ++d) o.h4[d] = (__bf16)(acc[d] * linv);
        *(uint2*)(ych + (size_t)((oy + 1) * PW + ox + 1) * 96 + choff + h * 4) = o.u;
    }
}

// ---------------------------------------------------------------------------
// Axial row attention (over w). One block per (row y, head h); t = query x.
// Writes fp32 v1 workspace (consumed by axial_col as V).
// ---------------------------------------------------------------------------
__global__ __launch_bounds__(256) void axial_row_kernel(
    const float* __restrict__ fq, const float* __restrict__ kv,
    const float* __restrict__ lsc, float* __restrict__ v1)
{
    __shared__ float ks[240][4];
    __shared__ float vs[240][4];
    const int t = threadIdx.x;
    const int y = blockIdx.x, h = blockIdx.y;

    if (t < 240) {
        float k[4];
        float ksq = 0.f;
#pragma unroll
        for (int d = 0; d < 4; ++d) {
            k[d] = kv[(h * 4 + d) * PP + y * WW + t];
            vs[t][d] = kv[((8 + h) * 4 + d) * PP + y * WW + t];
            ksq += k[d] * k[d];
        }
        const float kinv = 1.0f / fmaxf(sqrtf(ksq), 1e-12f);
#pragma unroll
        for (int d = 0; d < 4; ++d) ks[t][d] = k[d] * kinv;
    }
    __syncthreads();
    if (t < 240) {
        float q[4];
        float qsq = 0.f;
#pragma unroll
        for (int d = 0; d < 4; ++d) {
            q[d] = fq[(h * 4 + d) * PP + y * WW + t];
            qsq += q[d] * q[d];
        }
        const float qinv = 1.0f / fmaxf(sqrtf(qsq), 1e-12f);
#pragma unroll
        for (int d = 0; d < 4; ++d) q[d] *= qinv;
        const float scale = __expf(fminf(lsc[h], LOG_MAX_C));
        float m = -1e30f, l = 0.f, acc[4] = {0, 0, 0, 0};
        for (int j = 0; j < 240; ++j) {
            const float s = (q[0] * ks[j][0] + q[1] * ks[j][1] +
                             q[2] * ks[j][2] + q[3] * ks[j][3]) * scale;
            const float mn = fmaxf(m, s);
            const float c = __expf(m - mn);
            const float p = __expf(s - mn);
            l = l * c + p;
#pragma unroll
            for (int d = 0; d < 4; ++d) acc[d] = acc[d] * c + p * vs[j][d];
            m = mn;
        }
        const float linv = 1.0f / l;
#pragma unroll
        for (int d = 0; d < 4; ++d)
            v1[(h * 4 + d) * PP + y * WW + t] = acc[d] * linv;
    }
}

// ---------------------------------------------------------------------------
// Axial column attention (over h), same normalized q/k, V = v1 (row output).
// Writes bf16 into ych at channel 64+h*4.
// ---------------------------------------------------------------------------
__global__ __launch_bounds__(256) void axial_col_kernel(
    const float* __restrict__ fq, const float* __restrict__ kv,
    const float* __restrict__ v1, const float* __restrict__ lsc,
    __bf16* __restrict__ ych)
{
    __shared__ float ks[240][4];
    __shared__ float vs[240][4];
    const int t = threadIdx.x;
    const int x = blockIdx.x, h = blockIdx.y;

    if (t < 240) {
        float k[4];
        float ksq = 0.f;
#pragma unroll
        for (int d = 0; d < 4; ++d) {
            k[d] = kv[(h * 4 + d) * PP + t * WW + x];
            vs[t][d] = v1[(h * 4 + d) * PP + t * WW + x];
            ksq += k[d] * k[d];
        }
        const float kinv = 1.0f / fmaxf(sqrtf(ksq), 1e-12f);
#pragma unroll
        for (int d = 0; d < 4; ++d) ks[t][d] = k[d] * kinv;
    }
    __syncthreads();
    if (t < 240) {
        float q[4];
        float qsq = 0.f;
#pragma unroll
        for (int d = 0; d < 4; ++d) {
            q[d] = fq[(h * 4 + d) * PP + t * WW + x];
            qsq += q[d] * q[d];
        }
        const float qinv = 1.0f / fmaxf(sqrtf(qsq), 1e-12f);
#pragma unroll
        for (int d = 0; d < 4; ++d) q[d] *= qinv;
        const float scale = __expf(fminf(lsc[h], LOG_MAX_C));
        float m = -1e30f, l = 0.f, acc[4] = {0, 0, 0, 0};
        for (int j = 0; j < 240; ++j) {
            const float s = (q[0] * ks[j][0] + q[1] * ks[j][1] +
                             q[2] * ks[j][2] + q[3] * ks[j][3]) * scale;
            const float mn = fmaxf(m, s);
            const float c = __expf(m - mn);
            const float p = __expf(s - mn);
            l = l * c + p;
#pragma unroll
            for (int d = 0; d < 4; ++d) acc[d] = acc[d] * c + p * vs[j][d];
            m = mn;
        }
        const float linv = 1.0f / l;
        union { __bf16 h4[4]; uint2 u; } o;
#pragma unroll
        for (int d = 0; d < 4; ++d) o.h4[d] = (__bf16)(acc[d] * linv);
        *(uint2*)(ych + (size_t)((t + 1) * PW + x + 1) * 96 + 64 + h * 4) = o.u;
    }
}

// ---------------------------------------------------------------------------
// Pipeline:
//   wt_transform x3; x -> xh (padded NHWC bf16)
//   conv_in (MFMA): xh -> xp (fp32 NCHW, 192ch); conv_f: xh -> fp (96ch)
//   zero ych (aliases xh; xh dead after convs); attention writes ych bf16
//   conv_out (MFMA): ych -> d_out (fp32 NCHW)
// Workspace (85.6 MB): xp 192P f32 | fp 96P f32 | v1 32P f32 |
//                      xh/ych 242*242*96 bf16 | wt_in | wt_f | wt_out
// ---------------------------------------------------------------------------
extern "C" void kernel_launch(void* const* d_in, const int* in_sizes, int n_in,
                              void* d_out, int out_size, void* d_ws, size_t ws_size,
                              hipStream_t stream)
{
    const float* x     = (const float*)d_in[0];
    const float* w_in  = (const float*)d_in[1];
    const float* b_in  = (const float*)d_in[2];
    const float* w_f   = (const float*)d_in[3];
    const float* b_f   = (const float*)d_in[4];
    const float* w_out = (const float*)d_in[5];
    const float* b_out = (const float*)d_in[6];
    const float* lsc   = (const float*)d_in[7];
    const float* lrlsc = (const float*)d_in[8];
    float* out = (float*)d_out;

    float* ws = (float*)d_ws;
    float* xp = ws;                    // 192*PP f32
    float* fp = xp + 192 * PP;         //  96*PP f32
    float* v1 = fp + 96 * PP;          //  32*PP f32
    __bf16* xh    = (__bf16*)(v1 + 32 * PP);          // 242*242*96 bf16 (= ych)
    __bf16* wt_in = xh + (size_t)PW * PW * 96;        // 9*192*96
    __bf16* wt_f  = wt_in + 9 * 192 * 96;             // 9*96*96
    __bf16* wt_o  = wt_f + 9 * 96 * 96;               // 9*96*96
    __bf16* ych   = xh;                                // alias: xh dead after convs

    // weight + input layout transforms
    wt_transform<<<(192 * 96 + 255) / 256, 256, 0, stream>>>(w_in, wt_in, 192);
    wt_transform<<<(96 * 96 + 255) / 256, 256, 0, stream>>>(w_f, wt_f, 96);
    wt_transform<<<(96 * 96 + 255) / 256, 256, 0, stream>>>(w_out, wt_o, 96);
    to_nhwc_pad<<<(PW * PW + 255) / 256, 256, 0, stream>>>(x, xh);

    // convs 1+2 (MFMA implicit GEMM)
    conv3x3_mfma<192><<<dim3(15, 30, 6), 256, 0, stream>>>(xh, wt_in, b_in, xp);
    conv3x3_mfma<96><<<dim3(15, 30, 3), 256, 0, stream>>>(xh, wt_f, b_f, fp);

    // reuse xh region as ych: zero (border must be 0; interior overwritten)
    const int n16 = (PW * PW * 96 * 2) / 16;
    zero_u4<<<(n16 + 255) / 256, 256, 0, stream>>>((uint4*)ych, n16);

    // attention branches -> ych (bf16, padded NHWC)
    win_attn_kernel<<<dim3(48, 48), 256, 0, stream>>>(fp, xp, lsc, ych, 0, 0, 0);
    win_attn_kernel<<<dim3(48, 48), 256, 0, stream>>>(fp + 32 * PP, xp + 64 * PP,
                                                      lsc, ych, 3, 2, 32);
    axial_row_kernel<<<dim3(240, 8), 256, 0, stream>>>(fp + 64 * PP, xp + 128 * PP,
                                                       lrlsc, v1);
    axial_col_kernel<<<dim3(240, 8), 256, 0, stream>>>(fp + 64 * PP, xp + 128 * PP,
                                                       v1, lrlsc, ych);

    // conv_out (MFMA)
    conv3x3_mfma<96><<<dim3(15, 30, 3), 256, 0, stream>>>(ych, wt_o, b_out, out);
}

// Round 4
// 404.938 us; speedup vs baseline: 3.7441x; 1.2196x over previous
//
#include <hip/hip_runtime.h>
#include <math.h>

#define HH 240
#define WW 240
#define PP (HH * WW)
#define PW 242              // padded width/height for NHWC bf16 conv input
#define LOG_MAX_C 4.605170185988091f  // log(100)
#define LOG2E 1.442695040888963f

typedef __bf16 bf16x8 __attribute__((ext_vector_type(8)));
typedef float  f32x4  __attribute__((ext_vector_type(4)));

// native v_exp_f32 (2^x) — NOT __exp2f (glibc macro collision on gfx950 build)
#define EXP2F(x) __builtin_amdgcn_exp2f(x)

// ---------------------------------------------------------------------------
// x (fp32 NCHW, 96ch, 240x240) -> xh (bf16 NHWC, zero-padded 242x242x96).
// ---------------------------------------------------------------------------
__global__ __launch_bounds__(256) void to_nhwc_pad(
    const float* __restrict__ in, __bf16* __restrict__ outh)
{
    const int p = blockIdx.x * 256 + threadIdx.x;
    if (p >= PW * PW) return;
    const int py = p / PW, px = p % PW;
    __bf16* op = outh + p * 96;
    union { __bf16 h[8]; uint4 u; } pk;
    if (py == 0 || py == PW - 1 || px == 0 || px == PW - 1) {
        pk.u = make_uint4(0, 0, 0, 0);
#pragma unroll
        for (int b = 0; b < 12; ++b) ((uint4*)op)[b] = pk.u;
    } else {
        const float* ip = in + (py - 1) * WW + (px - 1);
#pragma unroll
        for (int b = 0; b < 12; ++b) {
#pragma unroll
            for (int j = 0; j < 8; ++j)
                pk.h[j] = (__bf16)ip[(b * 8 + j) * PP];
            ((uint4*)op)[b] = pk.u;
        }
    }
}

// ---------------------------------------------------------------------------
// OIHW fp32 weights -> wt[tap][oc][ic] bf16 (tap = ky*3+kx).
// ---------------------------------------------------------------------------
__global__ __launch_bounds__(256) void wt_transform(
    const float* __restrict__ w, __bf16* __restrict__ wt, int OC)
{
    const int t = blockIdx.x * 256 + threadIdx.x;
    if (t >= OC * 96) return;
    const int oc = t / 96, ic = t % 96;
    const float* wp = w + t * 9;
#pragma unroll
    for (int tap = 0; tap < 9; ++tap)
        wt[(tap * OC + oc) * 96 + ic] = (__bf16)wp[tap];
}

__global__ __launch_bounds__(256) void zero_u4(uint4* __restrict__ p, int n16)
{
    const int i = blockIdx.x * 256 + threadIdx.x;
    if (i < n16) p[i] = make_uint4(0, 0, 0, 0);
}

// ---------------------------------------------------------------------------
// Implicit-GEMM 3x3 conv on MFMA (see round-2 comments; unchanged).
// C/D layout: col(px) = lane&15, row(oc) = quad*4 + reg  [m89-verified].
// ---------------------------------------------------------------------------
template <int OC>
__global__ __launch_bounds__(256) void conv3x3_mfma(
    const __bf16* __restrict__ xh, const __bf16* __restrict__ wt,
    const float* __restrict__ bias, float* __restrict__ out)
{
    const int wave = threadIdx.x >> 6;
    const int lane = threadIdx.x & 63;
    const int ln   = lane & 15;
    const int quad = lane >> 4;
    const int x0  = blockIdx.x * 16;
    const int y0  = blockIdx.y * 8;
    const int oc0 = blockIdx.z * 32;
    const int r0  = y0 + wave * 2;

    f32x4 acc[2][2] = {};

    const __bf16* aptr = wt + (size_t)(oc0 + ln) * 96 + quad * 8;
    const __bf16* bptr = xh + (size_t)(x0 + ln) * 96 + quad * 8;

#pragma unroll 1
    for (int dy = 0; dy < 3; ++dy) {
        const __bf16* brow0 = bptr + (size_t)(r0 + dy) * PW * 96;
        const __bf16* arow  = aptr + (size_t)(dy * 3) * OC * 96;
#pragma unroll
        for (int dx = 0; dx < 3; ++dx) {
            const __bf16* ap  = arow + (size_t)dx * OC * 96;
            const __bf16* bp0 = brow0 + dx * 96;
            const __bf16* bp1 = bp0 + PW * 96;
#pragma unroll
            for (int icb = 0; icb < 3; ++icb) {
                const int ic0 = icb * 32;
                bf16x8 a0 = *(const bf16x8*)(ap + ic0);
                bf16x8 a1 = *(const bf16x8*)(ap + 16 * 96 + ic0);
                bf16x8 b0 = *(const bf16x8*)(bp0 + ic0);
                bf16x8 b1 = *(const bf16x8*)(bp1 + ic0);
                acc[0][0] = __builtin_amdgcn_mfma_f32_16x16x32_bf16(a0, b0, acc[0][0], 0, 0, 0);
                acc[1][0] = __builtin_amdgcn_mfma_f32_16x16x32_bf16(a1, b0, acc[1][0], 0, 0, 0);
                acc[0][1] = __builtin_amdgcn_mfma_f32_16x16x32_bf16(a0, b1, acc[0][1], 0, 0, 0);
                acc[1][1] = __builtin_amdgcn_mfma_f32_16x16x32_bf16(a1, b1, acc[1][1], 0, 0, 0);
            }
        }
    }

#pragma unroll
    for (int mi = 0; mi < 2; ++mi) {
#pragma unroll
        for (int r = 0; r < 4; ++r) {
            const int oc = oc0 + mi * 16 + quad * 4 + r;
            const float bv = bias[oc];
#pragma unroll
            for (int ni = 0; ni < 2; ++ni) {
                out[(size_t)oc * PP + (r0 + ni) * WW + x0 + ln] = acc[mi][ni][r] + bv;
            }
        }
    }
}

// ---------------------------------------------------------------------------
// Window cosine attention, WS=5, NH=8, hd=4. Fixed-max single-pass softmax:
// cos*scale <= scale, so p = exp2(dot(q*scale*log2e, k) - scale*log2e) is
// exact softmax math with M = scale (arg >= -2*scale*log2e, no underflow at
// scale<=100 for the sum). One transcendental per key, no max pass.
// ---------------------------------------------------------------------------
__global__ __launch_bounds__(256) void win_attn_kernel(
    const float* __restrict__ fq, const float* __restrict__ kv,
    const float* __restrict__ lsc, __bf16* __restrict__ ych,
    int gshift, int sshift, int choff)
{
    __shared__ float ks[8][25][4];
    __shared__ float vs[8][25][4];
    const int t = threadIdx.x;
    const int wy = blockIdx.y, wx = blockIdx.x;
    const int h = t / 25, i = t % 25;
    float qn[4] = {0, 0, 0, 0};
    float negM2 = 0.f;
    int oy = 0, ox = 0;

    if (t < 200) {
        const int y = (wy * 5 + i / 5 + gshift) % HH;
        const int x = (wx * 5 + i % 5 + gshift) % WW;
        const int base = y * WW + x;
        float q[4], k[4];
        float qsq = 0.f, ksq = 0.f;
#pragma unroll
        for (int d = 0; d < 4; ++d) {
            q[d] = fq[(h * 4 + d) * PP + base];
            k[d] = kv[(h * 4 + d) * PP + base];
            vs[h][i][d] = kv[((8 + h) * 4 + d) * PP + base];
            qsq += q[d] * q[d];
            ksq += k[d] * k[d];
        }
        const float scale = __expf(fminf(lsc[h], LOG_MAX_C));
        const float qs = scale * LOG2E;
        negM2 = -qs;
        const float qinv = qs / fmaxf(sqrtf(qsq), 1e-12f);
        const float kinv = 1.0f / fmaxf(sqrtf(ksq), 1e-12f);
#pragma unroll
        for (int d = 0; d < 4; ++d) {
            qn[d] = q[d] * qinv;
            ks[h][i][d] = k[d] * kinv;
        }
        oy = (wy * 5 + i / 5 + sshift) % HH;
        ox = (wx * 5 + i % 5 + sshift) % WW;
    }
    __syncthreads();
    if (t < 200) {
        float l = 0.f, acc[4] = {0, 0, 0, 0};
#pragma unroll
        for (int j = 0; j < 25; ++j) {
            const float s = fmaf(qn[0], ks[h][j][0],
                            fmaf(qn[1], ks[h][j][1],
                            fmaf(qn[2], ks[h][j][2],
                            fmaf(qn[3], ks[h][j][3], negM2))));
            const float p = EXP2F(s);
            l += p;
#pragma unroll
            for (int d = 0; d < 4; ++d) acc[d] = fmaf(p, vs[h][j][d], acc[d]);
        }
        const float linv = 1.0f / l;
        union { __bf16 h4[4]; uint2 u; } o;
#pragma unroll
        for (int d = 0; d < 4; ++d) o.h4[d] = (__bf16)(acc[d] * linv);
        *(uint2*)(ych + (size_t)((oy + 1) * PW + ox + 1) * 96 + choff + h * 4) = o.u;
    }
}

// ---------------------------------------------------------------------------
// Axial row attention (over w). One block per (row y, head h); t = query x.
// Fixed-max single-pass softmax (same argument as win_attn).
// ---------------------------------------------------------------------------
__global__ __launch_bounds__(256) void axial_row_kernel(
    const float* __restrict__ fq, const float* __restrict__ kv,
    const float* __restrict__ lsc, float* __restrict__ v1)
{
    __shared__ float ks[240][4];
    __shared__ float vs[240][4];
    const int t = threadIdx.x;
    const int y = blockIdx.x, h = blockIdx.y;

    float q[4] = {0, 0, 0, 0};
    float negM2 = 0.f;
    if (t < 240) {
        float k[4];
        float ksq = 0.f, qsq = 0.f;
#pragma unroll
        for (int d = 0; d < 4; ++d) {
            k[d] = kv[(h * 4 + d) * PP + y * WW + t];
            vs[t][d] = kv[((8 + h) * 4 + d) * PP + y * WW + t];
            q[d] = fq[(h * 4 + d) * PP + y * WW + t];
            ksq += k[d] * k[d];
            qsq += q[d] * q[d];
        }
        const float kinv = 1.0f / fmaxf(sqrtf(ksq), 1e-12f);
#pragma unroll
        for (int d = 0; d < 4; ++d) ks[t][d] = k[d] * kinv;
        const float scale = __expf(fminf(lsc[h], LOG_MAX_C));
        const float qs = scale * LOG2E;
        negM2 = -qs;
        const float qinv = qs / fmaxf(sqrtf(qsq), 1e-12f);
#pragma unroll
        for (int d = 0; d < 4; ++d) q[d] *= qinv;
    }
    __syncthreads();
    if (t < 240) {
        float l = 0.f, acc[4] = {0, 0, 0, 0};
        for (int j = 0; j < 240; ++j) {
            const float s = fmaf(q[0], ks[j][0],
                            fmaf(q[1], ks[j][1],
                            fmaf(q[2], ks[j][2],
                            fmaf(q[3], ks[j][3], negM2))));
            const float p = EXP2F(s);
            l += p;
#pragma unroll
            for (int d = 0; d < 4; ++d) acc[d] = fmaf(p, vs[j][d], acc[d]);
        }
        const float linv = 1.0f / l;
#pragma unroll
        for (int d = 0; d < 4; ++d)
            v1[(h * 4 + d) * PP + y * WW + t] = acc[d] * linv;
    }
}

// ---------------------------------------------------------------------------
// Axial column attention (over h), same normalized q/k, V = v1 (row output).
// ---------------------------------------------------------------------------
__global__ __launch_bounds__(256) void axial_col_kernel(
    const float* __restrict__ fq, const float* __restrict__ kv,
    const float* __restrict__ v1, const float* __restrict__ lsc,
    __bf16* __restrict__ ych)
{
    __shared__ float ks[240][4];
    __shared__ float vs[240][4];
    const int t = threadIdx.x;
    const int x = blockIdx.x, h = blockIdx.y;

    float q[4] = {0, 0, 0, 0};
    float negM2 = 0.f;
    if (t < 240) {
        float k[4];
        float ksq = 0.f, qsq = 0.f;
#pragma unroll
        for (int d = 0; d < 4; ++d) {
            k[d] = kv[(h * 4 + d) * PP + t * WW + x];
            vs[t][d] = v1[(h * 4 + d) * PP + t * WW + x];
            q[d] = fq[(h * 4 + d) * PP + t * WW + x];
            ksq += k[d] * k[d];
            qsq += q[d] * q[d];
        }
        const float kinv = 1.0f / fmaxf(sqrtf(ksq), 1e-12f);
#pragma unroll
        for (int d = 0; d < 4; ++d) ks[t][d] = k[d] * kinv;
        const float scale = __expf(fminf(lsc[h], LOG_MAX_C));
        const float qs = scale * LOG2E;
        negM2 = -qs;
        const float qinv = qs / fmaxf(sqrtf(qsq), 1e-12f);
#pragma unroll
        for (int d = 0; d < 4; ++d) q[d] *= qinv;
    }
    __syncthreads();
    if (t < 240) {
        float l = 0.f, acc[4] = {0, 0, 0, 0};
        for (int j = 0; j < 240; ++j) {
            const float s = fmaf(q[0], ks[j][0],
                            fmaf(q[1], ks[j][1],
                            fmaf(q[2], ks[j][2],
                            fmaf(q[3], ks[j][3], negM2))));
            const float p = EXP2F(s);
            l += p;
#pragma unroll
            for (int d = 0; d < 4; ++d) acc[d] = fmaf(p, vs[j][d], acc[d]);
        }
        const float linv = 1.0f / l;
        union { __bf16 h4[4]; uint2 u; } o;
#pragma unroll
        for (int d = 0; d < 4; ++d) o.h4[d] = (__bf16)(acc[d] * linv);
        *(uint2*)(ych + (size_t)((t + 1) * PW + x + 1) * 96 + 64 + h * 4) = o.u;
    }
}

// ---------------------------------------------------------------------------
// Pipeline (see round-2 comments).
// ---------------------------------------------------------------------------
extern "C" void kernel_launch(void* const* d_in, const int* in_sizes, int n_in,
                              void* d_out, int out_size, void* d_ws, size_t ws_size,
                              hipStream_t stream)
{
    const float* x     = (const float*)d_in[0];
    const float* w_in  = (const float*)d_in[1];
    const float* b_in  = (const float*)d_in[2];
    const float* w_f   = (const float*)d_in[3];
    const float* b_f   = (const float*)d_in[4];
    const float* w_out = (const float*)d_in[5];
    const float* b_out = (const float*)d_in[6];
    const float* lsc   = (const float*)d_in[7];
    const float* lrlsc = (const float*)d_in[8];
    float* out = (float*)d_out;

    float* ws = (float*)d_ws;
    float* xp = ws;                    // 192*PP f32
    float* fp = xp + 192 * PP;         //  96*PP f32
    float* v1 = fp + 96 * PP;          //  32*PP f32
    __bf16* xh    = (__bf16*)(v1 + 32 * PP);          // 242*242*96 bf16 (= ych)
    __bf16* wt_in = xh + (size_t)PW * PW * 96;        // 9*192*96
    __bf16* wt_f  = wt_in + 9 * 192 * 96;             // 9*96*96
    __bf16* wt_o  = wt_f + 9 * 96 * 96;               // 9*96*96
    __bf16* ych   = xh;                                // alias: xh dead after convs

    wt_transform<<<(192 * 96 + 255) / 256, 256, 0, stream>>>(w_in, wt_in, 192);
    wt_transform<<<(96 * 96 + 255) / 256, 256, 0, stream>>>(w_f, wt_f, 96);
    wt_transform<<<(96 * 96 + 255) / 256, 256, 0, stream>>>(w_out, wt_o, 96);
    to_nhwc_pad<<<(PW * PW + 255) / 256, 256, 0, stream>>>(x, xh);

    conv3x3_mfma<192><<<dim3(15, 30, 6), 256, 0, stream>>>(xh, wt_in, b_in, xp);
    conv3x3_mfma<96><<<dim3(15, 30, 3), 256, 0, stream>>>(xh, wt_f, b_f, fp);

    const int n16 = (PW * PW * 96 * 2) / 16;
    zero_u4<<<(n16 + 255) / 256, 256, 0, stream>>>((uint4*)ych, n16);

    win_attn_kernel<<<dim3(48, 48), 256, 0, stream>>>(fp, xp, lsc, ych, 0, 0, 0);
    win_attn_kernel<<<dim3(48, 48), 256, 0, stream>>>(fp + 32 * PP, xp + 64 * PP,
                                                      lsc, ych, 3, 2, 32);
    axial_row_kernel<<<dim3(240, 8), 256, 0, stream>>>(fp + 64 * PP, xp + 128 * PP,
                                                       lrlsc, v1);
    axial_col_kernel<<<dim3(240, 8), 256, 0, stream>>>(fp + 64 * PP, xp + 128 * PP,
                                                       v1, lrlsc, ych);

    conv3x3_mfma<96><<<dim3(15, 30, 3), 256, 0, stream>>>(ych, wt_o, b_out, out);
}

// Round 5
// 372.649 us; speedup vs baseline: 4.0685x; 1.0866x over previous
//
#include <hip/hip_runtime.h>
#include <math.h>

#define HH 240
#define WW 240
#define PP (HH * WW)
#define PW 242              // padded width/height for NHWC bf16 conv input
#define LOG_MAX_C 4.605170185988091f  // log(100)
#define LOG2E 1.442695040888963f

typedef __bf16 bf16x8 __attribute__((ext_vector_type(8)));
typedef float  f32x4  __attribute__((ext_vector_type(4)));

// native v_exp_f32 (2^x) — NOT __exp2f (glibc macro collision on gfx950 build)
#define EXP2F(x) __builtin_amdgcn_exp2f(x)

// ---------------------------------------------------------------------------
// x (fp32 NCHW, 96ch, 240x240) -> xh (bf16 NHWC, zero-padded 242x242x96).
// ---------------------------------------------------------------------------
__global__ __launch_bounds__(256) void to_nhwc_pad(
    const float* __restrict__ in, __bf16* __restrict__ outh)
{
    const int p = blockIdx.x * 256 + threadIdx.x;
    if (p >= PW * PW) return;
    const int py = p / PW, px = p % PW;
    __bf16* op = outh + p * 96;
    union { __bf16 h[8]; uint4 u; } pk;
    if (py == 0 || py == PW - 1 || px == 0 || px == PW - 1) {
        pk.u = make_uint4(0, 0, 0, 0);
#pragma unroll
        for (int b = 0; b < 12; ++b) ((uint4*)op)[b] = pk.u;
    } else {
        const float* ip = in + (py - 1) * WW + (px - 1);
#pragma unroll
        for (int b = 0; b < 12; ++b) {
#pragma unroll
            for (int j = 0; j < 8; ++j)
                pk.h[j] = (__bf16)ip[(b * 8 + j) * PP];
            ((uint4*)op)[b] = pk.u;
        }
    }
}

// ---------------------------------------------------------------------------
// OIHW fp32 weights -> wt[tap][oc][ic] bf16 (tap = ky*3+kx).
// ---------------------------------------------------------------------------
__global__ __launch_bounds__(256) void wt_transform(
    const float* __restrict__ w, __bf16* __restrict__ wt, int OC)
{
    const int t = blockIdx.x * 256 + threadIdx.x;
    if (t >= OC * 96) return;
    const int oc = t / 96, ic = t % 96;
    const float* wp = w + t * 9;
#pragma unroll
    for (int tap = 0; tap < 9; ++tap)
        wt[(tap * OC + oc) * 96 + ic] = (__bf16)wp[tap];
}

// ---------------------------------------------------------------------------
// Zero only the 1-px border ring of ych (interior is fully overwritten by the
// three attention branches: ch0-31 win0, ch32-63 win1, ch64-95 axial_col).
// ---------------------------------------------------------------------------
__global__ __launch_bounds__(256) void zero_border(__bf16* __restrict__ ych)
{
    const int idx = blockIdx.x * 256 + threadIdx.x;
    if (idx >= 4 * PW) return;
    const int g = idx / PW, i = idx % PW;
    int py, px;
    if (g == 0)      { py = 0;      px = i; }
    else if (g == 1) { py = PW - 1; px = i; }
    else if (g == 2) { py = i;      px = 0; }
    else             { py = i;      px = PW - 1; }
    uint4* op = (uint4*)(ych + (size_t)(py * PW + px) * 96);
#pragma unroll
    for (int b = 0; b < 12; ++b) op[b] = make_uint4(0, 0, 0, 0);
}

// ---------------------------------------------------------------------------
// Implicit-GEMM 3x3 conv on MFMA, v2: MT m-tiles (oc) x 4 n-tiles (rows) per
// wave. Loads/MFMA = (MT+4)/(4*MT): 0.5 at MT=4, 0.75 at MT=2 (was 1.0).
// Fully unrolled 27-k-step body gives the scheduler independent loads to
// hoist (round-4 profile: VGPR=44, all pipes <9% busy -> latency-bound with
// ~6 loads in flight; this raises per-wave ILP 4x).
// Block 256 thr = 4 waves stacked in y: covers MT*16 oc x 16x x 16y.
// C/D layout: col(px) = lane&15, row(oc) = quad*4 + reg  [m89-verified].
// ---------------------------------------------------------------------------
template <int OC, int MT>
__global__ __launch_bounds__(256) void conv3x3_mfma(
    const __bf16* __restrict__ xh, const __bf16* __restrict__ wt,
    const float* __restrict__ bias, float* __restrict__ out)
{
    const int wave = threadIdx.x >> 6;
    const int lane = threadIdx.x & 63;
    const int ln   = lane & 15;
    const int quad = lane >> 4;
    const int x0  = blockIdx.x * 16;
    const int y0  = blockIdx.y * 16;
    const int oc0 = blockIdx.z * (MT * 16);
    const int r0  = y0 + wave * 4;

    f32x4 acc[MT][4] = {};

    const __bf16* ab = wt + (size_t)(oc0 + ln) * 96 + quad * 8;
    const __bf16* bb = xh + (size_t)(x0 + ln) * 96 + quad * 8;

#pragma unroll
    for (int dy = 0; dy < 3; ++dy) {
#pragma unroll
        for (int dx = 0; dx < 3; ++dx) {
            const int tap = dy * 3 + dx;
            const __bf16* ap = ab + (size_t)tap * OC * 96;
            const __bf16* bp = bb + ((size_t)(r0 + dy) * PW + dx) * 96;
#pragma unroll
            for (int icb = 0; icb < 3; ++icb) {
                const int ic0 = icb * 32;
                bf16x8 a[MT], b[4];
#pragma unroll
                for (int mi = 0; mi < MT; ++mi)
                    a[mi] = *(const bf16x8*)(ap + (size_t)mi * 16 * 96 + ic0);
#pragma unroll
                for (int ni = 0; ni < 4; ++ni)
                    b[ni] = *(const bf16x8*)(bp + (size_t)ni * PW * 96 + ic0);
#pragma unroll
                for (int mi = 0; mi < MT; ++mi)
#pragma unroll
                    for (int ni = 0; ni < 4; ++ni)
                        acc[mi][ni] = __builtin_amdgcn_mfma_f32_16x16x32_bf16(
                            a[mi], b[ni], acc[mi][ni], 0, 0, 0);
            }
        }
    }

#pragma unroll
    for (int mi = 0; mi < MT; ++mi) {
#pragma unroll
        for (int r = 0; r < 4; ++r) {
            const int oc = oc0 + mi * 16 + quad * 4 + r;
            const float bv = bias[oc];
#pragma unroll
            for (int ni = 0; ni < 4; ++ni) {
                out[(size_t)oc * PP + (r0 + ni) * WW + x0 + ln] = acc[mi][ni][r] + bv;
            }
        }
    }
}

// ---------------------------------------------------------------------------
// Window cosine attention, WS=5, NH=8, hd=4. Fixed-max single-pass softmax:
// cos*scale <= scale, so p = exp2(dot(q*scale*log2e, k) - scale*log2e) is
// exact softmax math with M = scale. One transcendental per key, no max pass.
// ---------------------------------------------------------------------------
__global__ __launch_bounds__(256) void win_attn_kernel(
    const float* __restrict__ fq, const float* __restrict__ kv,
    const float* __restrict__ lsc, __bf16* __restrict__ ych,
    int gshift, int sshift, int choff)
{
    __shared__ float ks[8][25][4];
    __shared__ float vs[8][25][4];
    const int t = threadIdx.x;
    const int wy = blockIdx.y, wx = blockIdx.x;
    const int h = t / 25, i = t % 25;
    float qn[4] = {0, 0, 0, 0};
    float negM2 = 0.f;
    int oy = 0, ox = 0;

    if (t < 200) {
        const int y = (wy * 5 + i / 5 + gshift) % HH;
        const int x = (wx * 5 + i % 5 + gshift) % WW;
        const int base = y * WW + x;
        float q[4], k[4];
        float qsq = 0.f, ksq = 0.f;
#pragma unroll
        for (int d = 0; d < 4; ++d) {
            q[d] = fq[(h * 4 + d) * PP + base];
            k[d] = kv[(h * 4 + d) * PP + base];
            vs[h][i][d] = kv[((8 + h) * 4 + d) * PP + base];
            qsq += q[d] * q[d];
            ksq += k[d] * k[d];
        }
        const float scale = __expf(fminf(lsc[h], LOG_MAX_C));
        const float qs = scale * LOG2E;
        negM2 = -qs;
        const float qinv = qs / fmaxf(sqrtf(qsq), 1e-12f);
        const float kinv = 1.0f / fmaxf(sqrtf(ksq), 1e-12f);
#pragma unroll
        for (int d = 0; d < 4; ++d) {
            qn[d] = q[d] * qinv;
            ks[h][i][d] = k[d] * kinv;
        }
        oy = (wy * 5 + i / 5 + sshift) % HH;
        ox = (wx * 5 + i % 5 + sshift) % WW;
    }
    __syncthreads();
    if (t < 200) {
        float l = 0.f, acc[4] = {0, 0, 0, 0};
#pragma unroll
        for (int j = 0; j < 25; ++j) {
            const float s = fmaf(qn[0], ks[h][j][0],
                            fmaf(qn[1], ks[h][j][1],
                            fmaf(qn[2], ks[h][j][2],
                            fmaf(qn[3], ks[h][j][3], negM2))));
            const float p = EXP2F(s);
            l += p;
#pragma unroll
            for (int d = 0; d < 4; ++d) acc[d] = fmaf(p, vs[h][j][d], acc[d]);
        }
        const float linv = 1.0f / l;
        union { __bf16 h4[4]; uint2 u; } o;
#pragma unroll
        for (int d = 0; d < 4; ++d) o.h4[d] = (__bf16)(acc[d] * linv);
        *(uint2*)(ych + (size_t)((oy + 1) * PW + ox + 1) * 96 + choff + h * 4) = o.u;
    }
}

// ---------------------------------------------------------------------------
// Axial row attention (over w). One block per (row y, head h); t = query x.
// ---------------------------------------------------------------------------
__global__ __launch_bounds__(256) void axial_row_kernel(
    const float* __restrict__ fq, const float* __restrict__ kv,
    const float* __restrict__ lsc, float* __restrict__ v1)
{
    __shared__ float ks[240][4];
    __shared__ float vs[240][4];
    const int t = threadIdx.x;
    const int y = blockIdx.x, h = blockIdx.y;

    float q[4] = {0, 0, 0, 0};
    float negM2 = 0.f;
    if (t < 240) {
        float k[4];
        float ksq = 0.f, qsq = 0.f;
#pragma unroll
        for (int d = 0; d < 4; ++d) {
            k[d] = kv[(h * 4 + d) * PP + y * WW + t];
            vs[t][d] = kv[((8 + h) * 4 + d) * PP + y * WW + t];
            q[d] = fq[(h * 4 + d) * PP + y * WW + t];
            ksq += k[d] * k[d];
            qsq += q[d] * q[d];
        }
        const float kinv = 1.0f / fmaxf(sqrtf(ksq), 1e-12f);
#pragma unroll
        for (int d = 0; d < 4; ++d) ks[t][d] = k[d] * kinv;
        const float scale = __expf(fminf(lsc[h], LOG_MAX_C));
        const float qs = scale * LOG2E;
        negM2 = -qs;
        const float qinv = qs / fmaxf(sqrtf(qsq), 1e-12f);
#pragma unroll
        for (int d = 0; d < 4; ++d) q[d] *= qinv;
    }
    __syncthreads();
    if (t < 240) {
        float l = 0.f, acc[4] = {0, 0, 0, 0};
        for (int j = 0; j < 240; ++j) {
            const float s = fmaf(q[0], ks[j][0],
                            fmaf(q[1], ks[j][1],
                            fmaf(q[2], ks[j][2],
                            fmaf(q[3], ks[j][3], negM2))));
            const float p = EXP2F(s);
            l += p;
#pragma unroll
            for (int d = 0; d < 4; ++d) acc[d] = fmaf(p, vs[j][d], acc[d]);
        }
        const float linv = 1.0f / l;
#pragma unroll
        for (int d = 0; d < 4; ++d)
            v1[(h * 4 + d) * PP + y * WW + t] = acc[d] * linv;
    }
}

// ---------------------------------------------------------------------------
// Axial column attention (over h), same normalized q/k, V = v1 (row output).
// ---------------------------------------------------------------------------
__global__ __launch_bounds__(256) void axial_col_kernel(
    const float* __restrict__ fq, const float* __restrict__ kv,
    const float* __restrict__ v1, const float* __restrict__ lsc,
    __bf16* __restrict__ ych)
{
    __shared__ float ks[240][4];
    __shared__ float vs[240][4];
    const int t = threadIdx.x;
    const int x = blockIdx.x, h = blockIdx.y;

    float q[4] = {0, 0, 0, 0};
    float negM2 = 0.f;
    if (t < 240) {
        float k[4];
        float ksq = 0.f, qsq = 0.f;
#pragma unroll
        for (int d = 0; d < 4; ++d) {
            k[d] = kv[(h * 4 + d) * PP + t * WW + x];
            vs[t][d] = v1[(h * 4 + d) * PP + t * WW + x];
            q[d] = fq[(h * 4 + d) * PP + t * WW + x];
            ksq += k[d] * k[d];
            qsq += q[d] * q[d];
        }
        const float kinv = 1.0f / fmaxf(sqrtf(ksq), 1e-12f);
#pragma unroll
        for (int d = 0; d < 4; ++d) ks[t][d] = k[d] * kinv;
        const float scale = __expf(fminf(lsc[h], LOG_MAX_C));
        const float qs = scale * LOG2E;
        negM2 = -qs;
        const float qinv = qs / fmaxf(sqrtf(qsq), 1e-12f);
#pragma unroll
        for (int d = 0; d < 4; ++d) q[d] *= qinv;
    }
    __syncthreads();
    if (t < 240) {
        float l = 0.f, acc[4] = {0, 0, 0, 0};
        for (int j = 0; j < 240; ++j) {
            const float s = fmaf(q[0], ks[j][0],
                            fmaf(q[1], ks[j][1],
                            fmaf(q[2], ks[j][2],
                            fmaf(q[3], ks[j][3], negM2))));
            const float p = EXP2F(s);
            l += p;
#pragma unroll
            for (int d = 0; d < 4; ++d) acc[d] = fmaf(p, vs[j][d], acc[d]);
        }
        const float linv = 1.0f / l;
        union { __bf16 h4[4]; uint2 u; } o;
#pragma unroll
        for (int d = 0; d < 4; ++d) o.h4[d] = (__bf16)(acc[d] * linv);
        *(uint2*)(ych + (size_t)((t + 1) * PW + x + 1) * 96 + 64 + h * 4) = o.u;
    }
}

// ---------------------------------------------------------------------------
// Pipeline (see round-2 comments).
// ---------------------------------------------------------------------------
extern "C" void kernel_launch(void* const* d_in, const int* in_sizes, int n_in,
                              void* d_out, int out_size, void* d_ws, size_t ws_size,
                              hipStream_t stream)
{
    const float* x     = (const float*)d_in[0];
    const float* w_in  = (const float*)d_in[1];
    const float* b_in  = (const float*)d_in[2];
    const float* w_f   = (const float*)d_in[3];
    const float* b_f   = (const float*)d_in[4];
    const float* w_out = (const float*)d_in[5];
    const float* b_out = (const float*)d_in[6];
    const float* lsc   = (const float*)d_in[7];
    const float* lrlsc = (const float*)d_in[8];
    float* out = (float*)d_out;

    float* ws = (float*)d_ws;
    float* xp = ws;                    // 192*PP f32
    float* fp = xp + 192 * PP;         //  96*PP f32
    float* v1 = fp + 96 * PP;          //  32*PP f32
    __bf16* xh    = (__bf16*)(v1 + 32 * PP);          // 242*242*96 bf16 (= ych)
    __bf16* wt_in = xh + (size_t)PW * PW * 96;        // 9*192*96
    __bf16* wt_f  = wt_in + 9 * 192 * 96;             // 9*96*96
    __bf16* wt_o  = wt_f + 9 * 96 * 96;               // 9*96*96
    __bf16* ych   = xh;                                // alias: xh dead after convs

    wt_transform<<<(192 * 96 + 255) / 256, 256, 0, stream>>>(w_in, wt_in, 192);
    wt_transform<<<(96 * 96 + 255) / 256, 256, 0, stream>>>(w_f, wt_f, 96);
    wt_transform<<<(96 * 96 + 255) / 256, 256, 0, stream>>>(w_out, wt_o, 96);
    to_nhwc_pad<<<(PW * PW + 255) / 256, 256, 0, stream>>>(x, xh);

    // convs (MFMA implicit GEMM, v2 tiles): 16x16 px block, MT*16 oc
    conv3x3_mfma<192, 4><<<dim3(15, 15, 3), 256, 0, stream>>>(xh, wt_in, b_in, xp);
    conv3x3_mfma<96, 2><<<dim3(15, 15, 3), 256, 0, stream>>>(xh, wt_f, b_f, fp);

    // border-only clear of ych (interior fully overwritten by attention)
    zero_border<<<(4 * PW + 255) / 256, 256, 0, stream>>>(ych);

    win_attn_kernel<<<dim3(48, 48), 256, 0, stream>>>(fp, xp, lsc, ych, 0, 0, 0);
    win_attn_kernel<<<dim3(48, 48), 256, 0, stream>>>(fp + 32 * PP, xp + 64 * PP,
                                                      lsc, ych, 3, 2, 32);
    axial_row_kernel<<<dim3(240, 8), 256, 0, stream>>>(fp + 64 * PP, xp + 128 * PP,
                                                       lrlsc, v1);
    axial_col_kernel<<<dim3(240, 8), 256, 0, stream>>>(fp + 64 * PP, xp + 128 * PP,
                                                       v1, lrlsc, ych);

    conv3x3_mfma<96, 2><<<dim3(15, 15, 3), 256, 0, stream>>>(ych, wt_o, b_out, out);
}